// Round 3
// baseline (765.661 us; speedup 1.0000x reference)
//
#include <hip/hip_runtime.h>
#include <cmath>

#define DEV __device__ __forceinline__

namespace {

constexpr int Kp    = 127;          // patch tokens
constexpr int Mrows = 32 * Kp;      // 4064 = B*K
constexpr int Rred  = 128 * Kp;     // 16256 = D*K (flat reduction length)

DEV float q88(float x) {
  float r = rintf(x * 256.0f);                       // round half to even, like jnp.round
  r = fminf(fmaxf(r, -32768.0f), 32767.0f);
  return r * 0.00390625f;
}
DEV float sigmoid_(float x) { return 1.0f / (1.0f + expf(-x)); }

DEV void fma16(const float4 av, const float4 bv, float (&acc)[4][4]) {
  acc[0][0] = fmaf(av.x, bv.x, acc[0][0]); acc[0][1] = fmaf(av.x, bv.y, acc[0][1]);
  acc[0][2] = fmaf(av.x, bv.z, acc[0][2]); acc[0][3] = fmaf(av.x, bv.w, acc[0][3]);
  acc[1][0] = fmaf(av.y, bv.x, acc[1][0]); acc[1][1] = fmaf(av.y, bv.y, acc[1][1]);
  acc[1][2] = fmaf(av.y, bv.z, acc[1][2]); acc[1][3] = fmaf(av.y, bv.w, acc[1][3]);
  acc[2][0] = fmaf(av.z, bv.x, acc[2][0]); acc[2][1] = fmaf(av.z, bv.y, acc[2][1]);
  acc[2][2] = fmaf(av.z, bv.z, acc[2][2]); acc[2][3] = fmaf(av.z, bv.w, acc[2][3]);
  acc[3][0] = fmaf(av.w, bv.x, acc[3][0]); acc[3][1] = fmaf(av.w, bv.y, acc[3][1]);
  acc[3][2] = fmaf(av.w, bv.z, acc[3][2]); acc[3][3] = fmaf(av.w, bv.w, acc[3][3]);
}

// ---------------- K0: quantize small weights (and transpose w_patch to [j][c][d]) -------------
__global__ __launch_bounds__(256) void k_quant(
    const float* __restrict__ wproj, const float* __restrict__ bproj,
    const float* __restrict__ wpatch, const float* __restrict__ bpatch,
    const float* __restrict__ whead, const float* __restrict__ bhead,
    const float* __restrict__ bflat,
    float* __restrict__ wq_proj, float* __restrict__ bq_proj, float* __restrict__ wpq,
    float* __restrict__ bq_patch, float* __restrict__ wq_head, float* __restrict__ bq_head,
    float* __restrict__ bq_flat) {
  int i = blockIdx.x * 256 + threadIdx.x;
  if (i < 262144) {
    int j = i >> 14;          // /16384
    int c = (i >> 7) & 127;
    int d = i & 127;
    wpq[i] = q88(wpatch[(d * 128 + c) * 16 + j]);   // w_patch[d][c][j] -> wpq[j][c][d]
  }
  int t = i - 262144;
  if (t >= 0) {
    if      (t < 1024) wq_proj[t]         = q88(wproj[t]);
    else if (t < 1152) bq_proj[t - 1024]  = q88(bproj[t - 1024]);
    else if (t < 1280) bq_patch[t - 1152] = q88(bpatch[t - 1152]);
    else if (t < 1536) wq_head[t - 1280]  = q88(whead[t - 1280]);
    else if (t < 1538) bq_head[t - 1536]  = q88(bhead[t - 1536]);
    else if (t < 4610) bq_flat[t - 1538]  = q88(bflat[t - 1538]);
  }
}

// ---------------- K1: 1x1 conv (proj) -> xpq[b][l][c] (quantized) ----------------------------
__global__ __launch_bounds__(256) void k_proj(const float* __restrict__ x, const float* __restrict__ wq,
                                              const float* __restrict__ bq, float* __restrict__ xpq) {
  int bl0 = blockIdx.x * 16;          // 16 (b,l) rows per block; grid 2048
  int tid = threadIdx.x;
  __shared__ float xs[128];
  if (tid < 128) xs[tid] = q88(x[(size_t)bl0 * 8 + tid]);
  __syncthreads();
  int o = tid & 127;
  int half = tid >> 7;                // 0,1
  float wv[8];
#pragma unroll
  for (int c = 0; c < 8; ++c) wv[c] = wq[o * 8 + c];
  float bb = bq[o];
#pragma unroll
  for (int il = 0; il < 8; ++il) {
    int l_loc = half * 8 + il;
    float acc = bb;
#pragma unroll
    for (int c = 0; c < 8; ++c) acc = fmaf(xs[l_loc * 8 + c], wv[c], acc);
    xpq[(size_t)(bl0 + l_loc) * 128 + o] = q88(acc);
  }
}

// ---------------- K2: patch conv as 16 accumulated GEMMs, j-split x4 -------------------------
__global__ __launch_bounds__(256) void k_patch(const float* __restrict__ xpq, const float* __restrict__ wpq,
                                               float* __restrict__ partJ) {
  __shared__ __align__(16) float As[128][36];
  int mt = blockIdx.x, jg = blockIdx.y;
  int tid = threadIdx.x;
  int mr = tid & 31, c0 = (tid >> 5) * 16;
  int tn = tid & 31, tm8 = tid >> 5;
  int m0 = mt * 32;
  int g = m0 + mr;
  int bb = g / 127, kq = g % 127;
  float acc[4][4] = {};
  for (int jj = 0; jj < 4; ++jj) {
    int j = jg * 4 + jj;
    const float* src = xpq + ((size_t)bb * 1024 + kq * 8 + j) * 128 + c0;
    __syncthreads();
#pragma unroll
    for (int q = 0; q < 4; ++q) {
      float4 v = *reinterpret_cast<const float4*>(src + q * 4);
      As[c0 + q * 4 + 0][mr] = v.x;
      As[c0 + q * 4 + 1][mr] = v.y;
      As[c0 + q * 4 + 2][mr] = v.z;
      As[c0 + q * 4 + 3][mr] = v.w;
    }
    __syncthreads();
    const float* wp = wpq + (size_t)j * 16384 + tn * 4;
#pragma unroll 4
    for (int c = 0; c < 128; ++c) {
      float4 bv = *reinterpret_cast<const float4*>(wp + c * 128);
      float4 av = *reinterpret_cast<const float4*>(&As[c][tm8 * 4]);
      fma16(av, bv, acc);
    }
  }
  float* dst = partJ + ((size_t)jg * Mrows + m0) * 128 + tn * 4;
#pragma unroll
  for (int i = 0; i < 4; ++i) {
    float4 o4 = make_float4(acc[i][0], acc[i][1], acc[i][2], acc[i][3]);
    *reinterpret_cast<float4*>(dst + (size_t)(tm8 * 4 + i) * 128) = o4;
  }
}

// ---------------- K3: combine j-partials + bias, q88, add positional encoding ----------------
__global__ __launch_bounds__(256) void k_combine(const float* __restrict__ partJ, const float* __restrict__ bqp,
                                                 const float* __restrict__ pe, const float* __restrict__ pesc,
                                                 float* __restrict__ h) {
  int i = blockIdx.x * 256 + threadIdx.x;  // < 520192
  int n = i & 127;
  int gq = i >> 7;
  int k = gq % 127;
  float s = partJ[i] + partJ[520192 + i] + partJ[2 * 520192 + i] + partJ[3 * 520192 + i] + bqp[n];
  h[i] = q88(s) + pesc[0] * pe[k * 128 + n];
}

// ---------------- K4: layernorm + (hn @ w_in -> silu -> u) / (hn @ w_gate -> silu -> g) -------
__global__ __launch_bounds__(256) void k_ln_ug(const float* __restrict__ h, const float* __restrict__ lng,
                                               const float* __restrict__ lnb, const float* __restrict__ Win,
                                               const float* __restrict__ Wgate, float* __restrict__ u,
                                               float* __restrict__ gbuf) {
  __shared__ __align__(16) float As[128][36];
  __shared__ float2 lnpart[8][32];
  __shared__ float mean_s[32], inv_s[32];
  const float* W = blockIdx.y ? Wgate : Win;
  float* out = blockIdx.y ? gbuf : u;
  int tid = threadIdx.x;
  int mr = tid & 31, c0 = (tid >> 5) * 16;
  int m0 = blockIdx.x * 32;
  const float* src = h + (size_t)(m0 + mr) * 128 + c0;
  float s1 = 0.f, s2 = 0.f;
#pragma unroll
  for (int q = 0; q < 4; ++q) {
    float4 v = *reinterpret_cast<const float4*>(src + q * 4);
    As[c0 + q * 4 + 0][mr] = v.x;
    As[c0 + q * 4 + 1][mr] = v.y;
    As[c0 + q * 4 + 2][mr] = v.z;
    As[c0 + q * 4 + 3][mr] = v.w;
    s1 += v.x + v.y + v.z + v.w;
    s2 = fmaf(v.x, v.x, s2); s2 = fmaf(v.y, v.y, s2);
    s2 = fmaf(v.z, v.z, s2); s2 = fmaf(v.w, v.w, s2);
  }
  lnpart[tid >> 5][mr] = make_float2(s1, s2);
  __syncthreads();
  if (tid < 32) {
    float s = 0.f, ss = 0.f;
#pragma unroll
    for (int j = 0; j < 8; ++j) { float2 p = lnpart[j][tid]; s += p.x; ss += p.y; }
    float mn = s * (1.0f / 128.0f);
    float var = ss * (1.0f / 128.0f) - mn * mn;
    mean_s[tid] = mn;
    inv_s[tid] = rsqrtf(var + 1e-5f);
  }
  __syncthreads();
  float mnv = mean_s[mr], invv = inv_s[mr];
#pragma unroll
  for (int q = 0; q < 16; ++q) {
    int c = c0 + q;
    As[c][mr] = (As[c][mr] - mnv) * invv * lng[c] + lnb[c];
  }
  __syncthreads();
  int tn = tid & 31, tm8 = tid >> 5;
  float acc[4][4] = {};
  const float* wp = W + tn * 4;
#pragma unroll 4
  for (int c = 0; c < 128; ++c) {
    float4 bv = *reinterpret_cast<const float4*>(wp + c * 128);
    float4 av = *reinterpret_cast<const float4*>(&As[c][tm8 * 4]);
    fma16(av, bv, acc);
  }
  float* dst = out + (size_t)m0 * 128 + tn * 4;
#pragma unroll
  for (int i = 0; i < 4; ++i) {
    float4 o4;
    { float xq = q88(acc[i][0]); o4.x = q88(xq * sigmoid_(xq)); }
    { float xq = q88(acc[i][1]); o4.y = q88(xq * sigmoid_(xq)); }
    { float xq = q88(acc[i][2]); o4.z = q88(xq * sigmoid_(xq)); }
    { float xq = q88(acc[i][3]); o4.w = q88(xq * sigmoid_(xq)); }
    *reinterpret_cast<float4*>(dst + (size_t)(tm8 * 4 + i) * 128) = o4;
  }
}

// ---------------- K5: lam = q88(sigmoid(q88(wdt @ u[b] + b_dt))) as tiled GEMM ---------------
// grid (32 b, 4 t-tiles), 256 threads; out tile 32t x 128d; K = 127 (k)
__global__ __launch_bounds__(256) void k_lamg(const float* __restrict__ u, const float* __restrict__ wdt,
                                              const float* __restrict__ bdt, float* __restrict__ lam) {
  __shared__ __align__(16) float Wk[32][36];    // [k][t]
  __shared__ __align__(16) float Us[32][132];   // [k][d]
  int b = blockIdx.x, tt = blockIdx.y;
  int t0 = tt * 32;
  int tid = threadIdx.x;
  int dg = tid & 31, tg = tid >> 5;   // out: t = t0 + tg*4 + ti, d = dg*4 + di
  float acc[4][4] = {};
  const float* ub = u + (size_t)b * (127 * 128);
  for (int k0 = 0; k0 < 127; k0 += 32) {
    __syncthreads();
    {  // stage Wk: wdt[t0+t][k0+k] -> Wk[k][t]
      int k = tid & 31, tl = tid >> 5;
#pragma unroll
      for (int q = 0; q < 4; ++q) {
        int t = tl + 8 * q;
        int tg2 = t0 + t, kg = k0 + k;
        float v = (tg2 < 127 && kg < 127) ? wdt[tg2 * 127 + kg] : 0.f;
        Wk[k][t] = v;
      }
    }
    {  // stage Us: u[b][k0+k][d] -> Us[k][d]
      int dq = tid & 7, k = tid >> 3;
      int kg = k0 + k;
      const float* srcp = ub + (size_t)kg * 128 + dq * 16;
#pragma unroll
      for (int q = 0; q < 4; ++q) {
        float4 v = make_float4(0.f, 0.f, 0.f, 0.f);
        if (kg < 127) v = *reinterpret_cast<const float4*>(srcp + q * 4);
        *reinterpret_cast<float4*>(&Us[k][dq * 16 + q * 4]) = v;
      }
    }
    __syncthreads();
#pragma unroll 4
    for (int k = 0; k < 32; ++k) {
      float4 tv = *reinterpret_cast<const float4*>(&Wk[k][tg * 4]);
      float4 dv = *reinterpret_cast<const float4*>(&Us[k][dg * 4]);
      fma16(tv, dv, acc);
    }
  }
#pragma unroll
  for (int ti = 0; ti < 4; ++ti) {
    int t = t0 + tg * 4 + ti;
    if (t < 127) {
      float bb = bdt[t];
      float4 o4;
      o4.x = q88(sigmoid_(q88(acc[ti][0] + bb)));
      o4.y = q88(sigmoid_(q88(acc[ti][1] + bb)));
      o4.z = q88(sigmoid_(q88(acc[ti][2] + bb)));
      o4.w = q88(sigmoid_(q88(acc[ti][3] + bb)));
      *reinterpret_cast<float4*>(lam + ((size_t)b * 127 + t) * 128 + dg * 4) = o4;
    }
  }
}

// ---------------- K6: sequential scan, fused with p = y*g (in-place over lam buffer) ---------
__global__ __launch_bounds__(128) void k_scan(const float* __restrict__ u, const float* __restrict__ gbuf,
                                              float* __restrict__ lamp) {
  int gt = blockIdx.x * 128 + threadIdx.x;  // 1024 threads = B*D/4
  int b = gt >> 5, d4 = (gt & 31) * 4;
  size_t base = (size_t)b * (127 * 128) + d4;
  float4 s = make_float4(0.f, 0.f, 0.f, 0.f);
  for (int t = 0; t < 127; ++t) {
    size_t idx = base + (size_t)t * 128;
    float4 lm = *reinterpret_cast<const float4*>(lamp + idx);
    float4 uu = *reinterpret_cast<const float4*>(u + idx);
    float4 gg = *reinterpret_cast<const float4*>(gbuf + idx);
    s.x = lm.x * s.x + (1.0f - lm.x) * uu.x;
    s.y = lm.y * s.y + (1.0f - lm.y) * uu.y;
    s.z = lm.z * s.z + (1.0f - lm.z) * uu.z;
    s.w = lm.w * s.w + (1.0f - lm.w) * uu.w;
    float4 p = make_float4(s.x * gg.x, s.y * gg.y, s.z * gg.z, s.w * gg.w);
    *reinterpret_cast<float4*>(lamp + idx) = p;
  }
}

// ---------------- K7: h += p @ w_out --------------------------------------------------------
__global__ __launch_bounds__(256) void k_outproj(const float* __restrict__ p, const float* __restrict__ W,
                                                 float* __restrict__ h) {
  __shared__ __align__(16) float As[128][36];
  int tid = threadIdx.x;
  int mr = tid & 31, c0 = (tid >> 5) * 16;
  int m0 = blockIdx.x * 32;
  const float* src = p + (size_t)(m0 + mr) * 128 + c0;
#pragma unroll
  for (int q = 0; q < 4; ++q) {
    float4 v = *reinterpret_cast<const float4*>(src + q * 4);
    As[c0 + q * 4 + 0][mr] = v.x;
    As[c0 + q * 4 + 1][mr] = v.y;
    As[c0 + q * 4 + 2][mr] = v.z;
    As[c0 + q * 4 + 3][mr] = v.w;
  }
  __syncthreads();
  int tn = tid & 31, tm8 = tid >> 5;
  float acc[4][4] = {};
  const float* wp = W + tn * 4;
#pragma unroll 4
  for (int c = 0; c < 128; ++c) {
    float4 bv = *reinterpret_cast<const float4*>(wp + c * 128);
    float4 av = *reinterpret_cast<const float4*>(&As[c][tm8 * 4]);
    fma16(av, bv, acc);
  }
  float* dst = h + (size_t)m0 * 128 + tn * 4;
#pragma unroll
  for (int i = 0; i < 4; ++i) {
    float4 hv = *reinterpret_cast<float4*>(dst + (size_t)(tm8 * 4 + i) * 128);
    hv.x += acc[i][0]; hv.y += acc[i][1]; hv.z += acc[i][2]; hv.w += acc[i][3];
    *reinterpret_cast<float4*>(dst + (size_t)(tm8 * 4 + i) * 128) = hv;
  }
}

// ---------------- K8: final layernorm + q88 + (implicit) transpose to [b][r] ----------------
__global__ __launch_bounds__(128) void k_lnf(const float* __restrict__ h, const float* __restrict__ gg,
                                             const float* __restrict__ bb, float* __restrict__ xp2q) {
  int row = blockIdx.x;  // 4064
  int d = threadIdx.x;
  float v = h[(size_t)row * 128 + d];
  __shared__ float red[128];
  __shared__ float mn_s, inv_s;
  red[d] = v;
  __syncthreads();
  for (int off = 64; off > 0; off >>= 1) {
    if (d < off) red[d] += red[d + off];
    __syncthreads();
  }
  if (d == 0) mn_s = red[0] * (1.0f / 128.0f);
  __syncthreads();
  float dv = v - mn_s;
  red[d] = dv * dv;
  __syncthreads();
  for (int off = 64; off > 0; off >>= 1) {
    if (d < off) red[d] += red[d + off];
    __syncthreads();
  }
  if (d == 0) inv_s = rsqrtf(red[0] * (1.0f / 128.0f) + 1e-5f);
  __syncthreads();
  float hn = (v - mn_s) * inv_s * gg[d] + bb[d];
  int b = row / 127, k = row % 127;
  xp2q[((size_t)b * 128 + d) * 127 + k] = q88(hn);
}

// ---------------- K9: flat contraction; W direct global->reg, A in 4KB LDS ------------------
// C[b,o] = sum_r Aq[b,r]*q88(Wf[o,r]).  64 threads: og=tid&15 (8 o's), bg=tid>>4 (8 b's).
// o-tile 128, r-split 256 wide (rs = 0..63, virtual R = 16384 zero-padded).
// A prescaled by 1/256 in LDS; q88(w) folded to rintf(w*256) (|w|<<128 so clamp dead).
__global__ __launch_bounds__(64) void k_flat(const float* __restrict__ Aq, const float* __restrict__ Wf,
                                             float* __restrict__ partF) {
  __shared__ float As[32][32];   // [r][b] * (1/256)
  int ot = blockIdx.x, rs = blockIdx.y;
  int tid = threadIdx.x;
  int og = tid & 15, bg = tid >> 4;
  int o0 = ot * 128;
  int r0 = rs * 256;
  float acc[8][8] = {};
  size_t orow[8];
#pragma unroll
  for (int i = 0; i < 8; ++i) orow[i] = (size_t)(o0 + og * 8 + i) * Rred;

  float4 wbuf[2][8];
  // prologue: load quad 0 of chunk 0
  {
    int rc = r0; if (rc > Rred - 4) rc = Rred - 4;
#pragma unroll
    for (int i = 0; i < 8; ++i)
      wbuf[0][i] = *reinterpret_cast<const float4*>(Wf + orow[i] + rc);
  }

  int sb = tid >> 1, srq = tid & 1;    // staging: b-row, r-quad-half
  for (int ch = 0; ch < 256; ch += 32) {
    int rb = r0 + ch;
    __syncthreads();
    // stage A[rb..rb+32)[b] -> As[r][b] (prescaled)
#pragma unroll
    for (int q = 0; q < 4; ++q) {
      int rl = srq * 16 + q * 4;
      int rr = rb + rl;
      float4 v = make_float4(0.f, 0.f, 0.f, 0.f);
      if (rr < Rred) v = *reinterpret_cast<const float4*>(Aq + (size_t)sb * Rred + rr);
      As[rl + 0][sb] = v.x * 0.00390625f;
      As[rl + 1][sb] = v.y * 0.00390625f;
      As[rl + 2][sb] = v.z * 0.00390625f;
      As[rl + 3][sb] = v.w * 0.00390625f;
    }
    __syncthreads();
#pragma unroll
    for (int qd = 0; qd < 8; ++qd) {
      // prefetch next quad (possibly next chunk's quad 0)
      int rnext = rb + (qd + 1) * 4;         // == rb+32 == next chunk base when qd==7
      bool more = (ch + 32 < 256) || (qd < 7);
      if (more) {
        int rc = rnext; if (rc > Rred - 4) rc = Rred - 4;
#pragma unroll
        for (int i = 0; i < 8; ++i)
          wbuf[(qd + 1) & 1][i] = *reinterpret_cast<const float4*>(Wf + orow[i] + rc);
      }
      // compute with wbuf[qd&1]
#pragma unroll
      for (int j = 0; j < 4; ++j) {
        int rl = qd * 4 + j;
        float4 a0 = *reinterpret_cast<const float4*>(&As[rl][bg * 8]);
        float4 a1 = *reinterpret_cast<const float4*>(&As[rl][bg * 8 + 4]);
        float a[8] = {a0.x, a0.y, a0.z, a0.w, a1.x, a1.y, a1.z, a1.w};
#pragma unroll
        for (int i = 0; i < 8; ++i) {
          float4 wv = wbuf[qd & 1][i];
          float w = (j == 0) ? wv.x : (j == 1) ? wv.y : (j == 2) ? wv.z : wv.w;
          float wq = rintf(w * 256.0f);
#pragma unroll
          for (int bi = 0; bi < 8; ++bi)
            acc[bi][i] = fmaf(a[bi], wq, acc[bi][i]);
        }
      }
    }
  }
#pragma unroll
  for (int bi = 0; bi < 8; ++bi) {
    int b = bg * 8 + bi;
    float* dst = partF + ((size_t)rs * 32 + b) * 3072 + o0 + og * 8;
    *reinterpret_cast<float4*>(dst)     = make_float4(acc[bi][0], acc[bi][1], acc[bi][2], acc[bi][3]);
    *reinterpret_cast<float4*>(dst + 4) = make_float4(acc[bi][4], acc[bi][5], acc[bi][6], acc[bi][7]);
  }
}

// ---------------- K10: combine r-partials -> y_feat (q88) -> head conv1x1 --------------------
__global__ __launch_bounds__(256) void k_head(const float* __restrict__ partF, const float* __restrict__ bqf,
                                              const float* __restrict__ wqh, const float* __restrict__ bqh,
                                              float* __restrict__ out) {
  int b = blockIdx.x;
  int tid = threadIdx.x;
  __shared__ float yf[3072];
#pragma unroll
  for (int i = 0; i < 12; ++i) {
    int o = tid + 256 * i;
    float s = bqf[o];
    for (int rsq = 0; rsq < 64; ++rsq) s += partF[((size_t)rsq * 32 + b) * 3072 + o];
    yf[o] = q88(s);
  }
  __syncthreads();
  if (tid < 48) {
    int oh = tid / 24, f = tid % 24;
    float acc = bqh[oh];
    for (int d = 0; d < 128; ++d) acc = fmaf(yf[d * 24 + f], wqh[oh * 128 + d], acc);
    out[(size_t)b * 48 + oh * 24 + f] = q88(acc);
  }
}

}  // namespace

extern "C" void kernel_launch(void* const* d_in, const int* in_sizes, int n_in,
                              void* d_out, int out_size, void* d_ws, size_t ws_size,
                              hipStream_t stream) {
  const float* x      = (const float*)d_in[0];
  const float* wproj  = (const float*)d_in[1];
  const float* bproj  = (const float*)d_in[2];
  const float* wpatch = (const float*)d_in[3];
  const float* bpatch = (const float*)d_in[4];
  const float* pe     = (const float*)d_in[5];
  const float* pescal = (const float*)d_in[6];
  const float* lng    = (const float*)d_in[7];
  const float* lnb    = (const float*)d_in[8];
  const float* win    = (const float*)d_in[9];
  const float* wgate  = (const float*)d_in[10];
  const float* wout   = (const float*)d_in[11];
  const float* wdt    = (const float*)d_in[12];
  const float* bdt    = (const float*)d_in[13];
  const float* lnfg   = (const float*)d_in[14];
  const float* lnfb   = (const float*)d_in[15];
  const float* wflat  = (const float*)d_in[16];
  const float* bflat  = (const float*)d_in[17];
  const float* whead  = (const float*)d_in[18];
  const float* bhead  = (const float*)d_in[19];
  float* out = (float*)d_out;
  float* ws  = (float*)d_ws;

  // ws layout (float offsets)
  constexpr size_t O_WQPROJ  = 0;         // 1024
  constexpr size_t O_BQPROJ  = 1024;      // 128
  constexpr size_t O_WPQ     = 2048;      // 262144   [j][c][d]
  constexpr size_t O_BQPATCH = 264192;    // 128
  constexpr size_t O_WQHEAD  = 264320;    // 256
  constexpr size_t O_BQHEAD  = 264576;    // 2 (pad 128)
  constexpr size_t O_BQFLAT  = 264704;    // 3072
  constexpr size_t O_XPQ     = 267776;    // 4194304  [b][l][c]; later reused as partF
  constexpr size_t O_PARTJ   = 4462080;   // 4*520192
  constexpr size_t O_H       = 6542848;   // 520192   [b][k][d]
  constexpr size_t O_U       = 7063040;   // 520192
  constexpr size_t O_G       = 7583232;   // 520192
  constexpr size_t O_LAMP    = 8103424;   // 520192   lam, then p = y*g
  constexpr size_t O_XP2Q    = 8623616;   // 520192   [b][r] (= [b][d][k])
  constexpr size_t O_PARTF   = O_XPQ;     // 64*98304 = 6291456; xpq/partJ/h dead by k_flat

  k_quant<<<(262144 + 4610 + 255) / 256, 256, 0, stream>>>(
      wproj, bproj, wpatch, bpatch, whead, bhead, bflat,
      ws + O_WQPROJ, ws + O_BQPROJ, ws + O_WPQ, ws + O_BQPATCH,
      ws + O_WQHEAD, ws + O_BQHEAD, ws + O_BQFLAT);

  k_proj<<<2048, 256, 0, stream>>>(x, ws + O_WQPROJ, ws + O_BQPROJ, ws + O_XPQ);

  {
    dim3 g(127, 4);
    k_patch<<<g, 256, 0, stream>>>(ws + O_XPQ, ws + O_WPQ, ws + O_PARTJ);
  }
  k_combine<<<2032, 256, 0, stream>>>(ws + O_PARTJ, ws + O_BQPATCH, pe, pescal, ws + O_H);

  for (int i = 0; i < 4; ++i) {
    dim3 g4(127, 2);
    k_ln_ug<<<g4, 256, 0, stream>>>(ws + O_H, lng + i * 128, lnb + i * 128,
                                    win + (size_t)i * 16384, wgate + (size_t)i * 16384,
                                    ws + O_U, ws + O_G);
    {
      dim3 gl(32, 4);
      k_lamg<<<gl, 256, 0, stream>>>(ws + O_U, wdt + (size_t)i * 16129, bdt + (size_t)i * 127,
                                     ws + O_LAMP);
    }
    k_scan<<<8, 128, 0, stream>>>(ws + O_U, ws + O_G, ws + O_LAMP);
    k_outproj<<<127, 256, 0, stream>>>(ws + O_LAMP, wout + (size_t)i * 16384, ws + O_H);
  }

  k_lnf<<<4064, 128, 0, stream>>>(ws + O_H, lnfg, lnfb, ws + O_XP2Q);

  {
    dim3 g(24, 64);
    k_flat<<<g, 64, 0, stream>>>(ws + O_XP2Q, wflat, ws + O_PARTF);
  }
  k_head<<<32, 256, 0, stream>>>(ws + O_PARTF, ws + O_BQFLAT, ws + O_WQHEAD, ws + O_BQHEAD, out);
}

// Round 4
// 497.175 us; speedup vs baseline: 1.5400x; 1.5400x over previous
//
#include <hip/hip_runtime.h>
#include <cmath>

#define DEV __device__ __forceinline__

namespace {

constexpr int Kp    = 127;          // patch tokens
constexpr int Mrows = 32 * Kp;      // 4064 = B*K
constexpr int Rred  = 128 * Kp;     // 16256 = D*K (flat reduction length)

DEV float q88(float x) {
  float r = rintf(x * 256.0f);                       // round half to even, like jnp.round
  r = fminf(fmaxf(r, -32768.0f), 32767.0f);
  return r * 0.00390625f;
}
DEV float sigmoid_(float x) { return 1.0f / (1.0f + expf(-x)); }

DEV void fma16(const float4 av, const float4 bv, float (&acc)[4][4]) {
  acc[0][0] = fmaf(av.x, bv.x, acc[0][0]); acc[0][1] = fmaf(av.x, bv.y, acc[0][1]);
  acc[0][2] = fmaf(av.x, bv.z, acc[0][2]); acc[0][3] = fmaf(av.x, bv.w, acc[0][3]);
  acc[1][0] = fmaf(av.y, bv.x, acc[1][0]); acc[1][1] = fmaf(av.y, bv.y, acc[1][1]);
  acc[1][2] = fmaf(av.y, bv.z, acc[1][2]); acc[1][3] = fmaf(av.y, bv.w, acc[1][3]);
  acc[2][0] = fmaf(av.z, bv.x, acc[2][0]); acc[2][1] = fmaf(av.z, bv.y, acc[2][1]);
  acc[2][2] = fmaf(av.z, bv.z, acc[2][2]); acc[2][3] = fmaf(av.z, bv.w, acc[2][3]);
  acc[3][0] = fmaf(av.w, bv.x, acc[3][0]); acc[3][1] = fmaf(av.w, bv.y, acc[3][1]);
  acc[3][2] = fmaf(av.w, bv.z, acc[3][2]); acc[3][3] = fmaf(av.w, bv.w, acc[3][3]);
}

// ---------------- K0: quantize small weights (and transpose w_patch to [j][c][d]) -------------
__global__ __launch_bounds__(256) void k_quant(
    const float* __restrict__ wproj, const float* __restrict__ bproj,
    const float* __restrict__ wpatch, const float* __restrict__ bpatch,
    const float* __restrict__ whead, const float* __restrict__ bhead,
    const float* __restrict__ bflat,
    float* __restrict__ wq_proj, float* __restrict__ bq_proj, float* __restrict__ wpq,
    float* __restrict__ bq_patch, float* __restrict__ wq_head, float* __restrict__ bq_head,
    float* __restrict__ bq_flat) {
  int i = blockIdx.x * 256 + threadIdx.x;
  if (i < 262144) {
    int j = i >> 14;          // /16384
    int c = (i >> 7) & 127;
    int d = i & 127;
    wpq[i] = q88(wpatch[(d * 128 + c) * 16 + j]);   // w_patch[d][c][j] -> wpq[j][c][d]
  }
  int t = i - 262144;
  if (t >= 0) {
    if      (t < 1024) wq_proj[t]         = q88(wproj[t]);
    else if (t < 1152) bq_proj[t - 1024]  = q88(bproj[t - 1024]);
    else if (t < 1280) bq_patch[t - 1152] = q88(bpatch[t - 1152]);
    else if (t < 1536) wq_head[t - 1280]  = q88(whead[t - 1280]);
    else if (t < 1538) bq_head[t - 1536]  = q88(bhead[t - 1536]);
    else if (t < 4610) bq_flat[t - 1538]  = q88(bflat[t - 1538]);
  }
}

// ---------------- K1: 1x1 conv (proj) -> xpq[b][l][c] (quantized) ----------------------------
__global__ __launch_bounds__(256) void k_proj(const float* __restrict__ x, const float* __restrict__ wq,
                                              const float* __restrict__ bq, float* __restrict__ xpq) {
  int bl0 = blockIdx.x * 16;          // 16 (b,l) rows per block; grid 2048
  int tid = threadIdx.x;
  __shared__ float xs[128];
  if (tid < 128) xs[tid] = q88(x[(size_t)bl0 * 8 + tid]);
  __syncthreads();
  int o = tid & 127;
  int half = tid >> 7;                // 0,1
  float wv[8];
#pragma unroll
  for (int c = 0; c < 8; ++c) wv[c] = wq[o * 8 + c];
  float bb = bq[o];
#pragma unroll
  for (int il = 0; il < 8; ++il) {
    int l_loc = half * 8 + il;
    float acc = bb;
#pragma unroll
    for (int c = 0; c < 8; ++c) acc = fmaf(xs[l_loc * 8 + c], wv[c], acc);
    xpq[(size_t)(bl0 + l_loc) * 128 + o] = q88(acc);
  }
}

// ---------------- K2: patch conv as 16 accumulated GEMMs, j-split x4 -------------------------
__global__ __launch_bounds__(256) void k_patch(const float* __restrict__ xpq, const float* __restrict__ wpq,
                                               float* __restrict__ partJ) {
  __shared__ __align__(16) float As[128][36];
  int mt = blockIdx.x, jg = blockIdx.y;
  int tid = threadIdx.x;
  int mr = tid & 31, c0 = (tid >> 5) * 16;
  int tn = tid & 31, tm8 = tid >> 5;
  int m0 = mt * 32;
  int g = m0 + mr;
  int bb = g / 127, kq = g % 127;
  float acc[4][4] = {};
  for (int jj = 0; jj < 4; ++jj) {
    int j = jg * 4 + jj;
    const float* src = xpq + ((size_t)bb * 1024 + kq * 8 + j) * 128 + c0;
    __syncthreads();
#pragma unroll
    for (int q = 0; q < 4; ++q) {
      float4 v = *reinterpret_cast<const float4*>(src + q * 4);
      As[c0 + q * 4 + 0][mr] = v.x;
      As[c0 + q * 4 + 1][mr] = v.y;
      As[c0 + q * 4 + 2][mr] = v.z;
      As[c0 + q * 4 + 3][mr] = v.w;
    }
    __syncthreads();
    const float* wp = wpq + (size_t)j * 16384 + tn * 4;
#pragma unroll 4
    for (int c = 0; c < 128; ++c) {
      float4 bv = *reinterpret_cast<const float4*>(wp + c * 128);
      float4 av = *reinterpret_cast<const float4*>(&As[c][tm8 * 4]);
      fma16(av, bv, acc);
    }
  }
  float* dst = partJ + ((size_t)jg * Mrows + m0) * 128 + tn * 4;
#pragma unroll
  for (int i = 0; i < 4; ++i) {
    float4 o4 = make_float4(acc[i][0], acc[i][1], acc[i][2], acc[i][3]);
    *reinterpret_cast<float4*>(dst + (size_t)(tm8 * 4 + i) * 128) = o4;
  }
}

// ---------------- K3: combine j-partials + bias, q88, add positional encoding ----------------
__global__ __launch_bounds__(256) void k_combine(const float* __restrict__ partJ, const float* __restrict__ bqp,
                                                 const float* __restrict__ pe, const float* __restrict__ pesc,
                                                 float* __restrict__ h) {
  int i = blockIdx.x * 256 + threadIdx.x;  // < 520192
  int n = i & 127;
  int gq = i >> 7;
  int k = gq % 127;
  float s = partJ[i] + partJ[520192 + i] + partJ[2 * 520192 + i] + partJ[3 * 520192 + i] + bqp[n];
  h[i] = q88(s) + pesc[0] * pe[k * 128 + n];
}

// ---------------- K4: layernorm + (hn @ w_in -> silu -> u) / (hn @ w_gate -> silu -> g) -------
__global__ __launch_bounds__(256) void k_ln_ug(const float* __restrict__ h, const float* __restrict__ lng,
                                               const float* __restrict__ lnb, const float* __restrict__ Win,
                                               const float* __restrict__ Wgate, float* __restrict__ u,
                                               float* __restrict__ gbuf) {
  __shared__ __align__(16) float As[128][36];
  __shared__ float2 lnpart[8][32];
  __shared__ float mean_s[32], inv_s[32];
  const float* W = blockIdx.y ? Wgate : Win;
  float* out = blockIdx.y ? gbuf : u;
  int tid = threadIdx.x;
  int mr = tid & 31, c0 = (tid >> 5) * 16;
  int m0 = blockIdx.x * 32;
  const float* src = h + (size_t)(m0 + mr) * 128 + c0;
  float s1 = 0.f, s2 = 0.f;
#pragma unroll
  for (int q = 0; q < 4; ++q) {
    float4 v = *reinterpret_cast<const float4*>(src + q * 4);
    As[c0 + q * 4 + 0][mr] = v.x;
    As[c0 + q * 4 + 1][mr] = v.y;
    As[c0 + q * 4 + 2][mr] = v.z;
    As[c0 + q * 4 + 3][mr] = v.w;
    s1 += v.x + v.y + v.z + v.w;
    s2 = fmaf(v.x, v.x, s2); s2 = fmaf(v.y, v.y, s2);
    s2 = fmaf(v.z, v.z, s2); s2 = fmaf(v.w, v.w, s2);
  }
  lnpart[tid >> 5][mr] = make_float2(s1, s2);
  __syncthreads();
  if (tid < 32) {
    float s = 0.f, ss = 0.f;
#pragma unroll
    for (int j = 0; j < 8; ++j) { float2 p = lnpart[j][tid]; s += p.x; ss += p.y; }
    float mn = s * (1.0f / 128.0f);
    float var = ss * (1.0f / 128.0f) - mn * mn;
    mean_s[tid] = mn;
    inv_s[tid] = rsqrtf(var + 1e-5f);
  }
  __syncthreads();
  float mnv = mean_s[mr], invv = inv_s[mr];
#pragma unroll
  for (int q = 0; q < 16; ++q) {
    int c = c0 + q;
    As[c][mr] = (As[c][mr] - mnv) * invv * lng[c] + lnb[c];
  }
  __syncthreads();
  int tn = tid & 31, tm8 = tid >> 5;
  float acc[4][4] = {};
  const float* wp = W + tn * 4;
#pragma unroll 4
  for (int c = 0; c < 128; ++c) {
    float4 bv = *reinterpret_cast<const float4*>(wp + c * 128);
    float4 av = *reinterpret_cast<const float4*>(&As[c][tm8 * 4]);
    fma16(av, bv, acc);
  }
  float* dst = out + (size_t)m0 * 128 + tn * 4;
#pragma unroll
  for (int i = 0; i < 4; ++i) {
    float4 o4;
    { float xq = q88(acc[i][0]); o4.x = q88(xq * sigmoid_(xq)); }
    { float xq = q88(acc[i][1]); o4.y = q88(xq * sigmoid_(xq)); }
    { float xq = q88(acc[i][2]); o4.z = q88(xq * sigmoid_(xq)); }
    { float xq = q88(acc[i][3]); o4.w = q88(xq * sigmoid_(xq)); }
    *reinterpret_cast<float4*>(dst + (size_t)(tm8 * 4 + i) * 128) = o4;
  }
}

// ---------------- K5: lam = q88(sigmoid(q88(wdt @ u[b] + b_dt))) as tiled GEMM ---------------
// grid (32 b, 4 t-tiles), 256 threads; out tile 32t x 128d; K = 127 (k)
__global__ __launch_bounds__(256) void k_lamg(const float* __restrict__ u, const float* __restrict__ wdt,
                                              const float* __restrict__ bdt, float* __restrict__ lam) {
  __shared__ __align__(16) float Wk[32][36];    // [k][t]
  __shared__ __align__(16) float Us[32][132];   // [k][d]
  int b = blockIdx.x, tt = blockIdx.y;
  int t0 = tt * 32;
  int tid = threadIdx.x;
  int dg = tid & 31, tg = tid >> 5;   // out: t = t0 + tg*4 + ti, d = dg*4 + di
  float acc[4][4] = {};
  const float* ub = u + (size_t)b * (127 * 128);
  for (int k0 = 0; k0 < 127; k0 += 32) {
    __syncthreads();
    {  // stage Wk: wdt[t0+t][k0+k] -> Wk[k][t]
      int k = tid & 31, tl = tid >> 5;
#pragma unroll
      for (int q = 0; q < 4; ++q) {
        int t = tl + 8 * q;
        int tg2 = t0 + t, kg = k0 + k;
        float v = (tg2 < 127 && kg < 127) ? wdt[tg2 * 127 + kg] : 0.f;
        Wk[k][t] = v;
      }
    }
    {  // stage Us: u[b][k0+k][d] -> Us[k][d]
      int dq = tid & 7, k = tid >> 3;
      int kg = k0 + k;
      const float* srcp = ub + (size_t)kg * 128 + dq * 16;
#pragma unroll
      for (int q = 0; q < 4; ++q) {
        float4 v = make_float4(0.f, 0.f, 0.f, 0.f);
        if (kg < 127) v = *reinterpret_cast<const float4*>(srcp + q * 4);
        *reinterpret_cast<float4*>(&Us[k][dq * 16 + q * 4]) = v;
      }
    }
    __syncthreads();
#pragma unroll 4
    for (int k = 0; k < 32; ++k) {
      float4 tv = *reinterpret_cast<const float4*>(&Wk[k][tg * 4]);
      float4 dv = *reinterpret_cast<const float4*>(&Us[k][dg * 4]);
      fma16(tv, dv, acc);
    }
  }
#pragma unroll
  for (int ti = 0; ti < 4; ++ti) {
    int t = t0 + tg * 4 + ti;
    if (t < 127) {
      float bb = bdt[t];
      float4 o4;
      o4.x = q88(sigmoid_(q88(acc[ti][0] + bb)));
      o4.y = q88(sigmoid_(q88(acc[ti][1] + bb)));
      o4.z = q88(sigmoid_(q88(acc[ti][2] + bb)));
      o4.w = q88(sigmoid_(q88(acc[ti][3] + bb)));
      *reinterpret_cast<float4*>(lam + ((size_t)b * 127 + t) * 128 + dg * 4) = o4;
    }
  }
}

// ---------------- K6: sequential scan, fused with p = y*g (in-place over lam buffer) ---------
__global__ __launch_bounds__(128) void k_scan(const float* __restrict__ u, const float* __restrict__ gbuf,
                                              float* __restrict__ lamp) {
  int gt = blockIdx.x * 128 + threadIdx.x;  // 1024 threads = B*D/4
  int b = gt >> 5, d4 = (gt & 31) * 4;
  size_t base = (size_t)b * (127 * 128) + d4;
  float4 s = make_float4(0.f, 0.f, 0.f, 0.f);
  for (int t = 0; t < 127; ++t) {
    size_t idx = base + (size_t)t * 128;
    float4 lm = *reinterpret_cast<const float4*>(lamp + idx);
    float4 uu = *reinterpret_cast<const float4*>(u + idx);
    float4 gg = *reinterpret_cast<const float4*>(gbuf + idx);
    s.x = lm.x * s.x + (1.0f - lm.x) * uu.x;
    s.y = lm.y * s.y + (1.0f - lm.y) * uu.y;
    s.z = lm.z * s.z + (1.0f - lm.z) * uu.z;
    s.w = lm.w * s.w + (1.0f - lm.w) * uu.w;
    float4 p = make_float4(s.x * gg.x, s.y * gg.y, s.z * gg.z, s.w * gg.w);
    *reinterpret_cast<float4*>(lamp + idx) = p;
  }
}

// ---------------- K7: h += p @ w_out --------------------------------------------------------
__global__ __launch_bounds__(256) void k_outproj(const float* __restrict__ p, const float* __restrict__ W,
                                                 float* __restrict__ h) {
  __shared__ __align__(16) float As[128][36];
  int tid = threadIdx.x;
  int mr = tid & 31, c0 = (tid >> 5) * 16;
  int m0 = blockIdx.x * 32;
  const float* src = p + (size_t)(m0 + mr) * 128 + c0;
#pragma unroll
  for (int q = 0; q < 4; ++q) {
    float4 v = *reinterpret_cast<const float4*>(src + q * 4);
    As[c0 + q * 4 + 0][mr] = v.x;
    As[c0 + q * 4 + 1][mr] = v.y;
    As[c0 + q * 4 + 2][mr] = v.z;
    As[c0 + q * 4 + 3][mr] = v.w;
  }
  __syncthreads();
  int tn = tid & 31, tm8 = tid >> 5;
  float acc[4][4] = {};
  const float* wp = W + tn * 4;
#pragma unroll 4
  for (int c = 0; c < 128; ++c) {
    float4 bv = *reinterpret_cast<const float4*>(wp + c * 128);
    float4 av = *reinterpret_cast<const float4*>(&As[c][tm8 * 4]);
    fma16(av, bv, acc);
  }
  float* dst = h + (size_t)m0 * 128 + tn * 4;
#pragma unroll
  for (int i = 0; i < 4; ++i) {
    float4 hv = *reinterpret_cast<float4*>(dst + (size_t)(tm8 * 4 + i) * 128);
    hv.x += acc[i][0]; hv.y += acc[i][1]; hv.z += acc[i][2]; hv.w += acc[i][3];
    *reinterpret_cast<float4*>(dst + (size_t)(tm8 * 4 + i) * 128) = hv;
  }
}

// ---------------- K8: final layernorm + q88 + (implicit) transpose to [b][r] ----------------
__global__ __launch_bounds__(128) void k_lnf(const float* __restrict__ h, const float* __restrict__ gg,
                                             const float* __restrict__ bb, float* __restrict__ xp2q) {
  int row = blockIdx.x;  // 4064
  int d = threadIdx.x;
  float v = h[(size_t)row * 128 + d];
  __shared__ float red[128];
  __shared__ float mn_s, inv_s;
  red[d] = v;
  __syncthreads();
  for (int off = 64; off > 0; off >>= 1) {
    if (d < off) red[d] += red[d + off];
    __syncthreads();
  }
  if (d == 0) mn_s = red[0] * (1.0f / 128.0f);
  __syncthreads();
  float dv = v - mn_s;
  red[d] = dv * dv;
  __syncthreads();
  for (int off = 64; off > 0; off >>= 1) {
    if (d < off) red[d] += red[d + off];
    __syncthreads();
  }
  if (d == 0) inv_s = rsqrtf(red[0] * (1.0f / 128.0f) + 1e-5f);
  __syncthreads();
  float hn = (v - mn_s) * inv_s * gg[d] + bb[d];
  int b = row / 127, k = row % 127;
  xp2q[((size_t)b * 128 + d) * 127 + k] = q88(hn);
}

// ---------------- K9: flat contraction, 8b x 8o register tile, A+W in LDS --------------------
// C[b,o] = sum_r Aq[b,r]*q88(Wf[o,r]).
// grid (12 o-tiles x 64 rs), 128 threads. og=tid&31, bsub=tid>>5.
// Thread outputs: b = bsub*8+{0..7}; o = o0 + og*4+{0..3} and o0 + 128 + og*4+{0..3}.
// q88(W) folded into staging as rintf(w*256) (|w|max ~0.12 -> clamp dead);
// A prescaled by 2^-8 in LDS, so a_s * w_s == q88-exact product.
__global__ __launch_bounds__(128) void k_flat(const float* __restrict__ Aq, const float* __restrict__ Wf,
                                              float* __restrict__ partF) {
  __shared__ float As[32][36];    // [r][b], A * 2^-8
  __shared__ float Ws[32][260];   // [r][o], rintf(256*w)
  int ot = blockIdx.x, rs = blockIdx.y;
  int tid = threadIdx.x;
  int og = tid & 31, bsub = tid >> 5;
  int o0 = ot * 256;
  int r0 = rs * 256;               // virtual R = 16384, zero-padded past 16256
  float acc[8][8] = {};

  for (int ch = 0; ch < 256; ch += 32) {
    int rb = r0 + ch;
    __syncthreads();
    // ---- stage A: 32 r x 32 b. thread: b=tid&31, quads q0 and q0+4 ----
    {
      int b = tid & 31, q0 = tid >> 5;
#pragma unroll
      for (int qq = 0; qq < 2; ++qq) {
        int q = q0 + qq * 4;
        int rr = rb + q * 4;
        float4 v = make_float4(0.f, 0.f, 0.f, 0.f);
        if (rr < Rred) v = *reinterpret_cast<const float4*>(Aq + (size_t)b * Rred + rr);
        As[q * 4 + 0][b] = v.x * 0.00390625f;
        As[q * 4 + 1][b] = v.y * 0.00390625f;
        As[q * 4 + 2][b] = v.z * 0.00390625f;
        As[q * 4 + 3][b] = v.w * 0.00390625f;
      }
    }
    // ---- stage W: 32 r x 256 o. thread handles o-rows tid and tid+128 ----
#pragma unroll
    for (int pp = 0; pp < 2; ++pp) {
      int o_s = tid + pp * 128;
      const float* wrow = Wf + (size_t)(o0 + o_s) * Rred;
#pragma unroll
      for (int q = 0; q < 8; ++q) {
        int rr = rb + q * 4;
        float4 v = make_float4(0.f, 0.f, 0.f, 0.f);
        if (rr < Rred) v = *reinterpret_cast<const float4*>(wrow + rr);
        Ws[q * 4 + 0][o_s] = rintf(v.x * 256.0f);
        Ws[q * 4 + 1][o_s] = rintf(v.y * 256.0f);
        Ws[q * 4 + 2][o_s] = rintf(v.z * 256.0f);
        Ws[q * 4 + 3][o_s] = rintf(v.w * 256.0f);
      }
    }
    __syncthreads();
    // ---- compute 32 r-steps ----
#pragma unroll 4
    for (int rl = 0; rl < 32; ++rl) {
      float4 a0 = *reinterpret_cast<const float4*>(&As[rl][bsub * 8]);
      float4 a1 = *reinterpret_cast<const float4*>(&As[rl][bsub * 8 + 4]);
      float4 w0 = *reinterpret_cast<const float4*>(&Ws[rl][og * 4]);
      float4 w1 = *reinterpret_cast<const float4*>(&Ws[rl][og * 4 + 128]);
      float a[8] = {a0.x, a0.y, a0.z, a0.w, a1.x, a1.y, a1.z, a1.w};
      float w[8] = {w0.x, w0.y, w0.z, w0.w, w1.x, w1.y, w1.z, w1.w};
#pragma unroll
      for (int bi = 0; bi < 8; ++bi) {
#pragma unroll
        for (int oi = 0; oi < 8; ++oi)
          acc[bi][oi] = fmaf(a[bi], w[oi], acc[bi][oi]);
      }
    }
  }
  // ---- write partF[rs][b][o] ----
#pragma unroll
  for (int bi = 0; bi < 8; ++bi) {
    int b = bsub * 8 + bi;
    float* dst = partF + ((size_t)rs * 32 + b) * 3072 + o0;
    *reinterpret_cast<float4*>(dst + og * 4) =
        make_float4(acc[bi][0], acc[bi][1], acc[bi][2], acc[bi][3]);
    *reinterpret_cast<float4*>(dst + 128 + og * 4) =
        make_float4(acc[bi][4], acc[bi][5], acc[bi][6], acc[bi][7]);
  }
}

// ---------------- K10: combine r-partials -> y_feat (q88) -> head conv1x1 --------------------
__global__ __launch_bounds__(256) void k_head(const float* __restrict__ partF, const float* __restrict__ bqf,
                                              const float* __restrict__ wqh, const float* __restrict__ bqh,
                                              float* __restrict__ out) {
  int b = blockIdx.x;
  int tid = threadIdx.x;
  __shared__ float yf[3072];
#pragma unroll
  for (int i = 0; i < 12; ++i) {
    int o = tid + 256 * i;
    float s = bqf[o];
    for (int rsq = 0; rsq < 64; ++rsq) s += partF[((size_t)rsq * 32 + b) * 3072 + o];
    yf[o] = q88(s);
  }
  __syncthreads();
  if (tid < 48) {
    int oh = tid / 24, f = tid % 24;
    float acc = bqh[oh];
    for (int d = 0; d < 128; ++d) acc = fmaf(yf[d * 24 + f], wqh[oh * 128 + d], acc);
    out[(size_t)b * 48 + oh * 24 + f] = q88(acc);
  }
}

}  // namespace

extern "C" void kernel_launch(void* const* d_in, const int* in_sizes, int n_in,
                              void* d_out, int out_size, void* d_ws, size_t ws_size,
                              hipStream_t stream) {
  const float* x      = (const float*)d_in[0];
  const float* wproj  = (const float*)d_in[1];
  const float* bproj  = (const float*)d_in[2];
  const float* wpatch = (const float*)d_in[3];
  const float* bpatch = (const float*)d_in[4];
  const float* pe     = (const float*)d_in[5];
  const float* pescal = (const float*)d_in[6];
  const float* lng    = (const float*)d_in[7];
  const float* lnb    = (const float*)d_in[8];
  const float* win    = (const float*)d_in[9];
  const float* wgate  = (const float*)d_in[10];
  const float* wout   = (const float*)d_in[11];
  const float* wdt    = (const float*)d_in[12];
  const float* bdt    = (const float*)d_in[13];
  const float* lnfg   = (const float*)d_in[14];
  const float* lnfb   = (const float*)d_in[15];
  const float* wflat  = (const float*)d_in[16];
  const float* bflat  = (const float*)d_in[17];
  const float* whead  = (const float*)d_in[18];
  const float* bhead  = (const float*)d_in[19];
  float* out = (float*)d_out;
  float* ws  = (float*)d_ws;

  // ws layout (float offsets)
  constexpr size_t O_WQPROJ  = 0;         // 1024
  constexpr size_t O_BQPROJ  = 1024;      // 128
  constexpr size_t O_WPQ     = 2048;      // 262144   [j][c][d]
  constexpr size_t O_BQPATCH = 264192;    // 128
  constexpr size_t O_WQHEAD  = 264320;    // 256
  constexpr size_t O_BQHEAD  = 264576;    // 2 (pad 128)
  constexpr size_t O_BQFLAT  = 264704;    // 3072
  constexpr size_t O_XPQ     = 267776;    // 4194304  [b][l][c]; later reused as partF
  constexpr size_t O_PARTJ   = 4462080;   // 4*520192
  constexpr size_t O_H       = 6542848;   // 520192   [b][k][d]
  constexpr size_t O_U       = 7063040;   // 520192
  constexpr size_t O_G       = 7583232;   // 520192
  constexpr size_t O_LAMP    = 8103424;   // 520192   lam, then p = y*g
  constexpr size_t O_XP2Q    = 8623616;   // 520192   [b][r] (= [b][d][k])
  constexpr size_t O_PARTF   = O_XPQ;     // 64*98304 = 6291456; xpq/partJ/h dead by k_flat

  k_quant<<<(262144 + 4610 + 255) / 256, 256, 0, stream>>>(
      wproj, bproj, wpatch, bpatch, whead, bhead, bflat,
      ws + O_WQPROJ, ws + O_BQPROJ, ws + O_WPQ, ws + O_BQPATCH,
      ws + O_WQHEAD, ws + O_BQHEAD, ws + O_BQFLAT);

  k_proj<<<2048, 256, 0, stream>>>(x, ws + O_WQPROJ, ws + O_BQPROJ, ws + O_XPQ);

  {
    dim3 g(127, 4);
    k_patch<<<g, 256, 0, stream>>>(ws + O_XPQ, ws + O_WPQ, ws + O_PARTJ);
  }
  k_combine<<<2032, 256, 0, stream>>>(ws + O_PARTJ, ws + O_BQPATCH, pe, pescal, ws + O_H);

  for (int i = 0; i < 4; ++i) {
    dim3 g4(127, 2);
    k_ln_ug<<<g4, 256, 0, stream>>>(ws + O_H, lng + i * 128, lnb + i * 128,
                                    win + (size_t)i * 16384, wgate + (size_t)i * 16384,
                                    ws + O_U, ws + O_G);
    {
      dim3 gl(32, 4);
      k_lamg<<<gl, 256, 0, stream>>>(ws + O_U, wdt + (size_t)i * 16129, bdt + (size_t)i * 127,
                                     ws + O_LAMP);
    }
    k_scan<<<8, 128, 0, stream>>>(ws + O_U, ws + O_G, ws + O_LAMP);
    k_outproj<<<127, 256, 0, stream>>>(ws + O_LAMP, wout + (size_t)i * 16384, ws + O_H);
  }

  k_lnf<<<4064, 128, 0, stream>>>(ws + O_H, lnfg, lnfb, ws + O_XP2Q);

  {
    dim3 g(12, 64);
    k_flat<<<g, 128, 0, stream>>>(ws + O_XP2Q, wflat, ws + O_PARTF);
  }
  k_head<<<32, 256, 0, stream>>>(ws + O_PARTF, ws + O_BQFLAT, ws + O_WQHEAD, ws + O_BQHEAD, out);
}

// Round 5
// 445.288 us; speedup vs baseline: 1.7195x; 1.1165x over previous
//
#include <hip/hip_runtime.h>
#include <cmath>

#define DEV __device__ __forceinline__

namespace {

constexpr int Kp    = 127;          // patch tokens
constexpr int Mrows = 32 * Kp;      // 4064 = B*K
constexpr int Rred  = 128 * Kp;     // 16256 = D*K (flat reduction length)

DEV float q88(float x) {
  float r = rintf(x * 256.0f);                       // round half to even, like jnp.round
  r = fminf(fmaxf(r, -32768.0f), 32767.0f);
  return r * 0.00390625f;
}
DEV float sigmoid_(float x) { return 1.0f / (1.0f + expf(-x)); }

DEV void fma16(const float4 av, const float4 bv, float (&acc)[4][4]) {
  acc[0][0] = fmaf(av.x, bv.x, acc[0][0]); acc[0][1] = fmaf(av.x, bv.y, acc[0][1]);
  acc[0][2] = fmaf(av.x, bv.z, acc[0][2]); acc[0][3] = fmaf(av.x, bv.w, acc[0][3]);
  acc[1][0] = fmaf(av.y, bv.x, acc[1][0]); acc[1][1] = fmaf(av.y, bv.y, acc[1][1]);
  acc[1][2] = fmaf(av.y, bv.z, acc[1][2]); acc[1][3] = fmaf(av.y, bv.w, acc[1][3]);
  acc[2][0] = fmaf(av.z, bv.x, acc[2][0]); acc[2][1] = fmaf(av.z, bv.y, acc[2][1]);
  acc[2][2] = fmaf(av.z, bv.z, acc[2][2]); acc[2][3] = fmaf(av.z, bv.w, acc[2][3]);
  acc[3][0] = fmaf(av.w, bv.x, acc[3][0]); acc[3][1] = fmaf(av.w, bv.y, acc[3][1]);
  acc[3][2] = fmaf(av.w, bv.z, acc[3][2]); acc[3][3] = fmaf(av.w, bv.w, acc[3][3]);
}

// ---------------- K0: quantize small weights (and transpose w_patch to [j][c][d]) -------------
__global__ __launch_bounds__(256) void k_quant(
    const float* __restrict__ wproj, const float* __restrict__ bproj,
    const float* __restrict__ wpatch, const float* __restrict__ bpatch,
    const float* __restrict__ whead, const float* __restrict__ bhead,
    const float* __restrict__ bflat,
    float* __restrict__ wq_proj, float* __restrict__ bq_proj, float* __restrict__ wpq,
    float* __restrict__ bq_patch, float* __restrict__ wq_head, float* __restrict__ bq_head,
    float* __restrict__ bq_flat) {
  int i = blockIdx.x * 256 + threadIdx.x;
  if (i < 262144) {
    int j = i >> 14;          // /16384
    int c = (i >> 7) & 127;
    int d = i & 127;
    wpq[i] = q88(wpatch[(d * 128 + c) * 16 + j]);   // w_patch[d][c][j] -> wpq[j][c][d]
  }
  int t = i - 262144;
  if (t >= 0) {
    if      (t < 1024) wq_proj[t]         = q88(wproj[t]);
    else if (t < 1152) bq_proj[t - 1024]  = q88(bproj[t - 1024]);
    else if (t < 1280) bq_patch[t - 1152] = q88(bpatch[t - 1152]);
    else if (t < 1536) wq_head[t - 1280]  = q88(whead[t - 1280]);
    else if (t < 1538) bq_head[t - 1536]  = q88(bhead[t - 1536]);
    else if (t < 4610) bq_flat[t - 1538]  = q88(bflat[t - 1538]);
  }
}

// ---------------- K1: 1x1 conv (proj) -> xpq[b][l][c] (quantized) ----------------------------
__global__ __launch_bounds__(256) void k_proj(const float* __restrict__ x, const float* __restrict__ wq,
                                              const float* __restrict__ bq, float* __restrict__ xpq) {
  int bl0 = blockIdx.x * 16;          // 16 (b,l) rows per block; grid 2048
  int tid = threadIdx.x;
  __shared__ float xs[128];
  if (tid < 128) xs[tid] = q88(x[(size_t)bl0 * 8 + tid]);
  __syncthreads();
  int o = tid & 127;
  int half = tid >> 7;                // 0,1
  float wv[8];
#pragma unroll
  for (int c = 0; c < 8; ++c) wv[c] = wq[o * 8 + c];
  float bb = bq[o];
#pragma unroll
  for (int il = 0; il < 8; ++il) {
    int l_loc = half * 8 + il;
    float acc = bb;
#pragma unroll
    for (int c = 0; c < 8; ++c) acc = fmaf(xs[l_loc * 8 + c], wv[c], acc);
    xpq[(size_t)(bl0 + l_loc) * 128 + o] = q88(acc);
  }
}

// ---------------- K2: patch conv as 16 accumulated GEMMs, j-split x4 -------------------------
__global__ __launch_bounds__(256) void k_patch(const float* __restrict__ xpq, const float* __restrict__ wpq,
                                               float* __restrict__ partJ) {
  __shared__ __align__(16) float As[128][36];
  int mt = blockIdx.x, jg = blockIdx.y;
  int tid = threadIdx.x;
  int mr = tid & 31, c0 = (tid >> 5) * 16;
  int tn = tid & 31, tm8 = tid >> 5;
  int m0 = mt * 32;
  int g = m0 + mr;
  int bb = g / 127, kq = g % 127;
  float acc[4][4] = {};
  for (int jj = 0; jj < 4; ++jj) {
    int j = jg * 4 + jj;
    const float* src = xpq + ((size_t)bb * 1024 + kq * 8 + j) * 128 + c0;
    __syncthreads();
#pragma unroll
    for (int q = 0; q < 4; ++q) {
      float4 v = *reinterpret_cast<const float4*>(src + q * 4);
      As[c0 + q * 4 + 0][mr] = v.x;
      As[c0 + q * 4 + 1][mr] = v.y;
      As[c0 + q * 4 + 2][mr] = v.z;
      As[c0 + q * 4 + 3][mr] = v.w;
    }
    __syncthreads();
    const float* wp = wpq + (size_t)j * 16384 + tn * 4;
#pragma unroll 4
    for (int c = 0; c < 128; ++c) {
      float4 bv = *reinterpret_cast<const float4*>(wp + c * 128);
      float4 av = *reinterpret_cast<const float4*>(&As[c][tm8 * 4]);
      fma16(av, bv, acc);
    }
  }
  float* dst = partJ + ((size_t)jg * Mrows + m0) * 128 + tn * 4;
#pragma unroll
  for (int i = 0; i < 4; ++i) {
    float4 o4 = make_float4(acc[i][0], acc[i][1], acc[i][2], acc[i][3]);
    *reinterpret_cast<float4*>(dst + (size_t)(tm8 * 4 + i) * 128) = o4;
  }
}

// ---------------- K3: combine j-partials + bias, q88, add positional encoding ----------------
__global__ __launch_bounds__(256) void k_combine(const float* __restrict__ partJ, const float* __restrict__ bqp,
                                                 const float* __restrict__ pe, const float* __restrict__ pesc,
                                                 float* __restrict__ h) {
  int i = blockIdx.x * 256 + threadIdx.x;  // < 520192
  int n = i & 127;
  int gq = i >> 7;
  int k = gq % 127;
  float s = partJ[i] + partJ[520192 + i] + partJ[2 * 520192 + i] + partJ[3 * 520192 + i] + bqp[n];
  h[i] = q88(s) + pesc[0] * pe[k * 128 + n];
}

// ---------------- K4: LN + (hn@Win->silu->u) AND (hn@Wgate->silu->g) in one block -------------
__global__ __launch_bounds__(256) void k_ln_ug2(const float* __restrict__ h, const float* __restrict__ lng,
                                                const float* __restrict__ lnb, const float* __restrict__ Win,
                                                const float* __restrict__ Wgate, float* __restrict__ u,
                                                float* __restrict__ gbuf) {
  __shared__ __align__(16) float As[128][36];
  __shared__ float2 lnpart[8][32];
  __shared__ float mean_s[32], inv_s[32];
  int tid = threadIdx.x;
  int mr = tid & 31, c0 = (tid >> 5) * 16;
  int m0 = blockIdx.x * 32;
  const float* src = h + (size_t)(m0 + mr) * 128 + c0;
  float s1 = 0.f, s2 = 0.f;
#pragma unroll
  for (int q = 0; q < 4; ++q) {
    float4 v = *reinterpret_cast<const float4*>(src + q * 4);
    As[c0 + q * 4 + 0][mr] = v.x;
    As[c0 + q * 4 + 1][mr] = v.y;
    As[c0 + q * 4 + 2][mr] = v.z;
    As[c0 + q * 4 + 3][mr] = v.w;
    s1 += v.x + v.y + v.z + v.w;
    s2 = fmaf(v.x, v.x, s2); s2 = fmaf(v.y, v.y, s2);
    s2 = fmaf(v.z, v.z, s2); s2 = fmaf(v.w, v.w, s2);
  }
  lnpart[tid >> 5][mr] = make_float2(s1, s2);
  __syncthreads();
  if (tid < 32) {
    float s = 0.f, ss = 0.f;
#pragma unroll
    for (int j = 0; j < 8; ++j) { float2 p = lnpart[j][tid]; s += p.x; ss += p.y; }
    float mn = s * (1.0f / 128.0f);
    float var = ss * (1.0f / 128.0f) - mn * mn;
    mean_s[tid] = mn;
    inv_s[tid] = rsqrtf(var + 1e-5f);
  }
  __syncthreads();
  float mnv = mean_s[mr], invv = inv_s[mr];
#pragma unroll
  for (int q = 0; q < 16; ++q) {
    int c = c0 + q;
    As[c][mr] = (As[c][mr] - mnv) * invv * lng[c] + lnb[c];
  }
  __syncthreads();
  int tn = tid & 31, tm8 = tid >> 5;
  float accU[4][4] = {}, accG[4][4] = {};
  const float* wpU = Win + tn * 4;
  const float* wpG = Wgate + tn * 4;
#pragma unroll 2
  for (int c = 0; c < 128; ++c) {
    float4 av = *reinterpret_cast<const float4*>(&As[c][tm8 * 4]);
    float4 bu = *reinterpret_cast<const float4*>(wpU + c * 128);
    fma16(av, bu, accU);
    float4 bg = *reinterpret_cast<const float4*>(wpG + c * 128);
    fma16(av, bg, accG);
  }
  float* dstU = u + (size_t)m0 * 128 + tn * 4;
  float* dstG = gbuf + (size_t)m0 * 128 + tn * 4;
#pragma unroll
  for (int i = 0; i < 4; ++i) {
    float4 o4;
    { float xq = q88(accU[i][0]); o4.x = q88(xq * sigmoid_(xq)); }
    { float xq = q88(accU[i][1]); o4.y = q88(xq * sigmoid_(xq)); }
    { float xq = q88(accU[i][2]); o4.z = q88(xq * sigmoid_(xq)); }
    { float xq = q88(accU[i][3]); o4.w = q88(xq * sigmoid_(xq)); }
    *reinterpret_cast<float4*>(dstU + (size_t)(tm8 * 4 + i) * 128) = o4;
    float4 g4;
    { float xq = q88(accG[i][0]); g4.x = q88(xq * sigmoid_(xq)); }
    { float xq = q88(accG[i][1]); g4.y = q88(xq * sigmoid_(xq)); }
    { float xq = q88(accG[i][2]); g4.z = q88(xq * sigmoid_(xq)); }
    { float xq = q88(accG[i][3]); g4.w = q88(xq * sigmoid_(xq)); }
    *reinterpret_cast<float4*>(dstG + (size_t)(tm8 * 4 + i) * 128) = g4;
  }
}

// ---------------- K5: lam = q88(sigmoid(q88(wdt @ u[b] + b_dt))) as tiled GEMM ---------------
// grid (32 b, 4 t-tiles), 256 threads; out tile 32t x 128d; K = 127 (k)
__global__ __launch_bounds__(256) void k_lamg(const float* __restrict__ u, const float* __restrict__ wdt,
                                              const float* __restrict__ bdt, float* __restrict__ lam) {
  __shared__ __align__(16) float Wk[32][36];    // [k][t]
  __shared__ __align__(16) float Us[32][132];   // [k][d]
  int b = blockIdx.x, tt = blockIdx.y;
  int t0 = tt * 32;
  int tid = threadIdx.x;
  int dg = tid & 31, tg = tid >> 5;   // out: t = t0 + tg*4 + ti, d = dg*4 + di
  float acc[4][4] = {};
  const float* ub = u + (size_t)b * (127 * 128);
  for (int k0 = 0; k0 < 127; k0 += 32) {
    __syncthreads();
    {  // stage Wk: wdt[t0+t][k0+k] -> Wk[k][t]
      int k = tid & 31, tl = tid >> 5;
#pragma unroll
      for (int q = 0; q < 4; ++q) {
        int t = tl + 8 * q;
        int tg2 = t0 + t, kg = k0 + k;
        float v = (tg2 < 127 && kg < 127) ? wdt[tg2 * 127 + kg] : 0.f;
        Wk[k][t] = v;
      }
    }
    {  // stage Us: u[b][k0+k][d] -> Us[k][d]
      int dq = tid & 7, k = tid >> 3;
      int kg = k0 + k;
      const float* srcp = ub + (size_t)kg * 128 + dq * 16;
#pragma unroll
      for (int q = 0; q < 4; ++q) {
        float4 v = make_float4(0.f, 0.f, 0.f, 0.f);
        if (kg < 127) v = *reinterpret_cast<const float4*>(srcp + q * 4);
        *reinterpret_cast<float4*>(&Us[k][dq * 16 + q * 4]) = v;
      }
    }
    __syncthreads();
#pragma unroll 4
    for (int k = 0; k < 32; ++k) {
      float4 tv = *reinterpret_cast<const float4*>(&Wk[k][tg * 4]);
      float4 dv = *reinterpret_cast<const float4*>(&Us[k][dg * 4]);
      fma16(tv, dv, acc);
    }
  }
#pragma unroll
  for (int ti = 0; ti < 4; ++ti) {
    int t = t0 + tg * 4 + ti;
    if (t < 127) {
      float bb = bdt[t];
      float4 o4;
      o4.x = q88(sigmoid_(q88(acc[ti][0] + bb)));
      o4.y = q88(sigmoid_(q88(acc[ti][1] + bb)));
      o4.z = q88(sigmoid_(q88(acc[ti][2] + bb)));
      o4.w = q88(sigmoid_(q88(acc[ti][3] + bb)));
      *reinterpret_cast<float4*>(lam + ((size_t)b * 127 + t) * 128 + dg * 4) = o4;
    }
  }
}

// ---------------- K6: sequential scan + p = y*g; 1 block per batch, thread per d -------------
// 8-slot statically-indexed prefetch ring (rule-20 safe) hides L2 latency.
__global__ __launch_bounds__(128) void k_scan(const float* __restrict__ u, const float* __restrict__ gbuf,
                                              float* __restrict__ lamp) {
  int b = blockIdx.x, d = threadIdx.x;
  const size_t base = (size_t)b * (127 * 128) + d;
  float lm[8], uu[8], gg[8];
#pragma unroll
  for (int j = 0; j < 8; ++j) {
    size_t idx = base + (size_t)j * 128;
    lm[j] = lamp[idx]; uu[j] = u[idx]; gg[j] = gbuf[idx];
  }
  float s = 0.f;
  int t = 0;
  for (int it = 0; it < 15; ++it) {   // t = 0..119
#pragma unroll
    for (int j = 0; j < 8; ++j) {
      float l0 = lm[j], u0 = uu[j], g0 = gg[j];
      s = l0 * s + (1.0f - l0) * u0;
      lamp[base + (size_t)(t + j) * 128] = s * g0;
      int tn = t + j + 8;
      if (tn < 127) {
        size_t idx = base + (size_t)tn * 128;
        lm[j] = lamp[idx]; uu[j] = u[idx]; gg[j] = gbuf[idx];
      }
    }
    t += 8;
  }
  // tail t = 120..126 (slots 0..6)
#pragma unroll
  for (int j = 0; j < 7; ++j) {
    float l0 = lm[j], u0 = uu[j], g0 = gg[j];
    s = l0 * s + (1.0f - l0) * u0;
    lamp[base + (size_t)(120 + j) * 128] = s * g0;
  }
}

// ---------------- K7: h += p @ w_out --------------------------------------------------------
__global__ __launch_bounds__(256) void k_outproj(const float* __restrict__ p, const float* __restrict__ W,
                                                 float* __restrict__ h) {
  __shared__ __align__(16) float As[128][36];
  int tid = threadIdx.x;
  int mr = tid & 31, c0 = (tid >> 5) * 16;
  int m0 = blockIdx.x * 32;
  const float* src = p + (size_t)(m0 + mr) * 128 + c0;
#pragma unroll
  for (int q = 0; q < 4; ++q) {
    float4 v = *reinterpret_cast<const float4*>(src + q * 4);
    As[c0 + q * 4 + 0][mr] = v.x;
    As[c0 + q * 4 + 1][mr] = v.y;
    As[c0 + q * 4 + 2][mr] = v.z;
    As[c0 + q * 4 + 3][mr] = v.w;
  }
  __syncthreads();
  int tn = tid & 31, tm8 = tid >> 5;
  float acc[4][4] = {};
  const float* wp = W + tn * 4;
#pragma unroll 4
  for (int c = 0; c < 128; ++c) {
    float4 bv = *reinterpret_cast<const float4*>(wp + c * 128);
    float4 av = *reinterpret_cast<const float4*>(&As[c][tm8 * 4]);
    fma16(av, bv, acc);
  }
  float* dst = h + (size_t)m0 * 128 + tn * 4;
#pragma unroll
  for (int i = 0; i < 4; ++i) {
    float4 hv = *reinterpret_cast<float4*>(dst + (size_t)(tm8 * 4 + i) * 128);
    hv.x += acc[i][0]; hv.y += acc[i][1]; hv.z += acc[i][2]; hv.w += acc[i][3];
    *reinterpret_cast<float4*>(dst + (size_t)(tm8 * 4 + i) * 128) = hv;
  }
}

// ---------------- K8: final layernorm + q88 + (implicit) transpose to [b][r] ----------------
__global__ __launch_bounds__(128) void k_lnf(const float* __restrict__ h, const float* __restrict__ gg,
                                             const float* __restrict__ bb, float* __restrict__ xp2q) {
  int row = blockIdx.x;  // 4064
  int d = threadIdx.x;
  float v = h[(size_t)row * 128 + d];
  float a = v, sq = v * v;
#pragma unroll
  for (int off = 32; off >= 1; off >>= 1) {
    a += __shfl_xor(a, off, 64);
    sq += __shfl_xor(sq, off, 64);
  }
  __shared__ float ps[2][2];
  int w = d >> 6;
  if ((d & 63) == 0) { ps[w][0] = a; ps[w][1] = sq; }
  __syncthreads();
  float S1 = ps[0][0] + ps[1][0], S2 = ps[0][1] + ps[1][1];
  float mn = S1 * (1.0f / 128.0f);
  float inv = rsqrtf(S2 * (1.0f / 128.0f) - mn * mn + 1e-5f);
  float hn = (v - mn) * inv * gg[d] + bb[d];
  int b = row / 127, k = row % 127;
  xp2q[((size_t)b * 128 + d) * 127 + k] = q88(hn);
}

// ---------------- K9: flat contraction, 8b x 4o tile, reg-pipelined staging -----------------
// C[b,o] = sum_r Aq[b,r]*q88(Wf[o,r]).  grid (24 o-tiles x 64 rs), 128 threads.
// Per chunk (32 r): W 128o x 32r staged coalesced (4 lanes/row, 64B segments);
// global loads for chunk n+1 issued before computing chunk n (latency hidden).
// q88(W) folded to rintf(256w) at LDS store; A prescaled 2^-8 -> bit-exact product.
__global__ __launch_bounds__(128) void k_flat(const float* __restrict__ Aq, const float* __restrict__ Wf,
                                              float* __restrict__ partF) {
  __shared__ float As[32][36];    // [r][b] * 2^-8
  __shared__ float Ws[32][132];   // [r][o] rintf(256*w)
  int ot = blockIdx.x, rs = blockIdx.y;
  int tid = threadIdx.x;
  int og = tid & 31, bsub = tid >> 5;
  int o0 = ot * 128;
  int r0 = rs * 256;               // virtual R = 16384, zero-padded past 16256
  float acc[8][4] = {};

  const int wq4 = tid & 3;         // quad-pair within W row
  const int wrow_l = tid >> 2;     // 0..31, +32 per pass
  const int aq = tid >> 5;         // A quad group
  const int ab = tid & 31;         // A b-row

  float4 wreg[4][2];
  float4 areg[2];

  auto loadch = [&](int rb) {
#pragma unroll
    for (int p = 0; p < 4; ++p) {
      const float* wrow = Wf + (size_t)(o0 + wrow_l + 32 * p) * Rred;
#pragma unroll
      for (int q = 0; q < 2; ++q) {
        int rr = rb + wq4 * 8 + q * 4;
        wreg[p][q] = (rr < Rred) ? *reinterpret_cast<const float4*>(wrow + rr)
                                 : make_float4(0.f, 0.f, 0.f, 0.f);
      }
    }
#pragma unroll
    for (int i = 0; i < 2; ++i) {
      int rr = rb + aq * 4 + 16 * i;
      areg[i] = (rr < Rred) ? *reinterpret_cast<const float4*>(Aq + (size_t)ab * Rred + rr)
                            : make_float4(0.f, 0.f, 0.f, 0.f);
    }
  };

  loadch(r0);
  for (int ch = 0; ch < 8; ++ch) {
    __syncthreads();   // previous compute done reading LDS
    // store staged regs -> LDS (with quant transforms)
#pragma unroll
    for (int p = 0; p < 4; ++p) {
      int oc = wrow_l + 32 * p;
#pragma unroll
      for (int q = 0; q < 2; ++q) {
        int rl = wq4 * 8 + q * 4;
        Ws[rl + 0][oc] = rintf(wreg[p][q].x * 256.0f);
        Ws[rl + 1][oc] = rintf(wreg[p][q].y * 256.0f);
        Ws[rl + 2][oc] = rintf(wreg[p][q].z * 256.0f);
        Ws[rl + 3][oc] = rintf(wreg[p][q].w * 256.0f);
      }
    }
#pragma unroll
    for (int i = 0; i < 2; ++i) {
      int rl = aq * 4 + 16 * i;
      As[rl + 0][ab] = areg[i].x * 0.00390625f;
      As[rl + 1][ab] = areg[i].y * 0.00390625f;
      As[rl + 2][ab] = areg[i].z * 0.00390625f;
      As[rl + 3][ab] = areg[i].w * 0.00390625f;
    }
    __syncthreads();
    if (ch < 7) loadch(r0 + (ch + 1) * 32);   // in flight during compute
    // compute 32 r-steps
#pragma unroll 4
    for (int rl = 0; rl < 32; ++rl) {
      float4 w  = *reinterpret_cast<const float4*>(&Ws[rl][og * 4]);
      float4 a0 = *reinterpret_cast<const float4*>(&As[rl][bsub * 8]);
      float4 a1 = *reinterpret_cast<const float4*>(&As[rl][bsub * 8 + 4]);
      float a[8] = {a0.x, a0.y, a0.z, a0.w, a1.x, a1.y, a1.z, a1.w};
#pragma unroll
      for (int bi = 0; bi < 8; ++bi) {
        acc[bi][0] = fmaf(a[bi], w.x, acc[bi][0]);
        acc[bi][1] = fmaf(a[bi], w.y, acc[bi][1]);
        acc[bi][2] = fmaf(a[bi], w.z, acc[bi][2]);
        acc[bi][3] = fmaf(a[bi], w.w, acc[bi][3]);
      }
    }
  }
  // write partF[rs][b][o]
#pragma unroll
  for (int bi = 0; bi < 8; ++bi) {
    int b = bsub * 8 + bi;
    float* dst = partF + ((size_t)rs * 32 + b) * 3072 + o0 + og * 4;
    *reinterpret_cast<float4*>(dst) = make_float4(acc[bi][0], acc[bi][1], acc[bi][2], acc[bi][3]);
  }
}

// ---------------- K10: combine r-partials -> y_feat (q88) -> head conv1x1 --------------------
__global__ __launch_bounds__(256) void k_head(const float* __restrict__ partF, const float* __restrict__ bqf,
                                              const float* __restrict__ wqh, const float* __restrict__ bqh,
                                              float* __restrict__ out) {
  int b = blockIdx.x;
  int tid = threadIdx.x;
  __shared__ float yf[3072];
#pragma unroll
  for (int i = 0; i < 12; ++i) {
    int o = tid + 256 * i;
    float s = bqf[o];
    for (int rsq = 0; rsq < 64; ++rsq) s += partF[((size_t)rsq * 32 + b) * 3072 + o];
    yf[o] = q88(s);
  }
  __syncthreads();
  if (tid < 48) {
    int oh = tid / 24, f = tid % 24;
    float acc = bqh[oh];
    for (int d = 0; d < 128; ++d) acc = fmaf(yf[d * 24 + f], wqh[oh * 128 + d], acc);
    out[(size_t)b * 48 + oh * 24 + f] = q88(acc);
  }
}

}  // namespace

extern "C" void kernel_launch(void* const* d_in, const int* in_sizes, int n_in,
                              void* d_out, int out_size, void* d_ws, size_t ws_size,
                              hipStream_t stream) {
  const float* x      = (const float*)d_in[0];
  const float* wproj  = (const float*)d_in[1];
  const float* bproj  = (const float*)d_in[2];
  const float* wpatch = (const float*)d_in[3];
  const float* bpatch = (const float*)d_in[4];
  const float* pe     = (const float*)d_in[5];
  const float* pescal = (const float*)d_in[6];
  const float* lng    = (const float*)d_in[7];
  const float* lnb    = (const float*)d_in[8];
  const float* win    = (const float*)d_in[9];
  const float* wgate  = (const float*)d_in[10];
  const float* wout   = (const float*)d_in[11];
  const float* wdt    = (const float*)d_in[12];
  const float* bdt    = (const float*)d_in[13];
  const float* lnfg   = (const float*)d_in[14];
  const float* lnfb   = (const float*)d_in[15];
  const float* wflat  = (const float*)d_in[16];
  const float* bflat  = (const float*)d_in[17];
  const float* whead  = (const float*)d_in[18];
  const float* bhead  = (const float*)d_in[19];
  float* out = (float*)d_out;
  float* ws  = (float*)d_ws;

  // ws layout (float offsets)
  constexpr size_t O_WQPROJ  = 0;         // 1024
  constexpr size_t O_BQPROJ  = 1024;      // 128
  constexpr size_t O_WPQ     = 2048;      // 262144   [j][c][d]
  constexpr size_t O_BQPATCH = 264192;    // 128
  constexpr size_t O_WQHEAD  = 264320;    // 256
  constexpr size_t O_BQHEAD  = 264576;    // 2 (pad 128)
  constexpr size_t O_BQFLAT  = 264704;    // 3072
  constexpr size_t O_XPQ     = 267776;    // 4194304  [b][l][c]; later reused as partF
  constexpr size_t O_PARTJ   = 4462080;   // 4*520192
  constexpr size_t O_H       = 6542848;   // 520192   [b][k][d]
  constexpr size_t O_U       = 7063040;   // 520192
  constexpr size_t O_G       = 7583232;   // 520192
  constexpr size_t O_LAMP    = 8103424;   // 520192   lam, then p = y*g
  constexpr size_t O_XP2Q    = 8623616;   // 520192   [b][r] (= [b][d][k])
  constexpr size_t O_PARTF   = O_XPQ;     // 64*98304; xpq/partJ/h dead by k_flat

  k_quant<<<(262144 + 4610 + 255) / 256, 256, 0, stream>>>(
      wproj, bproj, wpatch, bpatch, whead, bhead, bflat,
      ws + O_WQPROJ, ws + O_BQPROJ, ws + O_WPQ, ws + O_BQPATCH,
      ws + O_WQHEAD, ws + O_BQHEAD, ws + O_BQFLAT);

  k_proj<<<2048, 256, 0, stream>>>(x, ws + O_WQPROJ, ws + O_BQPROJ, ws + O_XPQ);

  {
    dim3 g(127, 4);
    k_patch<<<g, 256, 0, stream>>>(ws + O_XPQ, ws + O_WPQ, ws + O_PARTJ);
  }
  k_combine<<<2032, 256, 0, stream>>>(ws + O_PARTJ, ws + O_BQPATCH, pe, pescal, ws + O_H);

  for (int i = 0; i < 4; ++i) {
    k_ln_ug2<<<127, 256, 0, stream>>>(ws + O_H, lng + i * 128, lnb + i * 128,
                                      win + (size_t)i * 16384, wgate + (size_t)i * 16384,
                                      ws + O_U, ws + O_G);
    {
      dim3 gl(32, 4);
      k_lamg<<<gl, 256, 0, stream>>>(ws + O_U, wdt + (size_t)i * 16129, bdt + (size_t)i * 127,
                                     ws + O_LAMP);
    }
    k_scan<<<32, 128, 0, stream>>>(ws + O_U, ws + O_G, ws + O_LAMP);
    k_outproj<<<127, 256, 0, stream>>>(ws + O_LAMP, wout + (size_t)i * 16384, ws + O_H);
  }

  k_lnf<<<4064, 128, 0, stream>>>(ws + O_H, lnfg, lnfb, ws + O_XP2Q);

  {
    dim3 g(24, 64);
    k_flat<<<g, 128, 0, stream>>>(ws + O_XP2Q, wflat, ws + O_PARTF);
  }
  k_head<<<32, 256, 0, stream>>>(ws + O_PARTF, ws + O_BQFLAT, ws + O_WQHEAD, ws + O_BQHEAD, out);
}